// Round 2
// baseline (94.747 us; speedup 1.0000x reference)
//
#include <hip/hip_runtime.h>

// DAA autoencoder: two masked-reduction layers.
//   layer0: h[b][o]   = min_i ( sel0[o][i] ? x[b][i] : 2.0f )   (t-norm)
//   layer1: out[b][o] = max_i ( sel1[o][i] ? h[b][i] : -1.0f )  (t-conorm)
// B=256, IN=1024, HID=512.
//
// R1 lesson: grid of 256 one-block-per-CU blocks (4 waves/CU) was
// latency-bound: Occupancy 9.5%, VALUBusy 13-24%. Fix: split the input
// reduction across S=4 wave-groups inside a 1024-thread block and combine
// partials in LDS. 4x the resident waves, same L2 traffic.
//
// Mapping: thread = (b = tid&255, s = tid>>8). Each thread partial-reduces
// its x-row chunk [s*CH, (s+1)*CH) for OT consecutive outputs. sel addresses
// are wave-uniform (same s across a wave) -> scalar loads. Offset == the
// reduction identity given acc init, so masked edges cost cndmask+min only.

template<int INF, int OT, int S, bool ISMIN>
__global__ __launch_bounds__(256 * S) void daa_layer(
    const float* __restrict__ in, const int* __restrict__ sel,
    float* __restrict__ out, int OUTF)
{
    constexpr int CH = INF / S;            // inputs per i-chunk
    const int tid = threadIdx.x;
    const int b   = tid & 255;             // batch row
    const int s   = tid >> 8;              // i-chunk
    const int o0  = blockIdx.x * OT;
    const float off = ISMIN ? 2.0f : -1.0f;

    float acc[OT];
#pragma unroll
    for (int u = 0; u < OT; ++u) acc[u] = off;

    const float4* __restrict__ xr = (const float4*)(in + (size_t)b * INF + s * CH);

#pragma unroll 4
    for (int i = 0; i < CH / 4; ++i) {
        const float4 xv = xr[i];
#pragma unroll
        for (int u = 0; u < OT; ++u) {
            const int4 sv = ((const int4*)(sel + (size_t)(o0 + u) * INF + s * CH))[i];
            const float v0 = sv.x ? xv.x : off;
            const float v1 = sv.y ? xv.y : off;
            const float v2 = sv.z ? xv.z : off;
            const float v3 = sv.w ? xv.w : off;
            if (ISMIN) {
                acc[u] = fminf(acc[u], fminf(fminf(v0, v1), fminf(v2, v3)));
            } else {
                acc[u] = fmaxf(acc[u], fmaxf(fmaxf(v0, v1), fmaxf(v2, v3)));
            }
        }
    }

    // Combine the S partials per (b, o) through LDS. Index stride over lanes
    // is 1 dword (b consecutive) -> bank-conflict-free.
    __shared__ float red[S][OT][256];
#pragma unroll
    for (int u = 0; u < OT; ++u) red[s][u][b] = acc[u];
    __syncthreads();

    if (s == 0) {
#pragma unroll
        for (int u = 0; u < OT; ++u) {
            float v = acc[u];
#pragma unroll
            for (int ss = 1; ss < S; ++ss) {
                const float r = red[ss][u][b];
                v = ISMIN ? fminf(v, r) : fmaxf(v, r);
            }
            out[(size_t)b * OUTF + (o0 + u)] = v;
        }
    }
}

extern "C" void kernel_launch(void* const* d_in, const int* in_sizes, int n_in,
                              void* d_out, int out_size, void* d_ws, size_t ws_size,
                              hipStream_t stream) {
    const float* x    = (const float*)d_in[0];  // [256,1024] f32
    const int*   sel0 = (const int*)d_in[1];    // [512,1024] i32
    const int*   sel1 = (const int*)d_in[2];    // [1024,512] i32
    float* out = (float*)d_out;                 // [256,1024] f32
    float* h   = (float*)d_ws;                  // [256,512]  f32 scratch (512 KB)

    // layer 0: 1024 -> 512, min. OT=2, S=4 -> 256 blocks x 1024 thr
    //          (1 block/CU, 16 waves/CU), ~256 MB L2 traffic.
    daa_layer<1024, 2, 4, true ><<<512 / 2,  1024, 0, stream>>>(x, sel0, h, 512);
    // layer 1: 512 -> 1024, max. OT=2, S=4 -> 512 blocks x 1024 thr
    //          (2 blocks/CU, up to 32 waves/CU), ~256 MB L2 traffic.
    daa_layer< 512, 2, 4, false><<<1024 / 2, 1024, 0, stream>>>(h, sel1, out, 1024);
}

// Round 3
// 55.990 us; speedup vs baseline: 1.6922x; 1.6922x over previous
//
#include <hip/hip_runtime.h>

// DAA autoencoder: two masked-reduction layers.
//   layer0: h[b][o]   = min_i ( sel0[o][i] ? x[b][i] : 2.0f )   (t-norm)
//   layer1: out[b][o] = max_i ( sel1[o][i] ? h[b][i] : -1.0f )  (t-conorm)
// B=256, IN=1024, HID=512.
//
// R1/R2 lesson: thread=batch makes x[b][i] a 64-line scattered gather per
// wave-load (~65K line-transactions/CU = the whole runtime). Fix: transpose
// x once to xT4[i4][b] (float4 = 4 consecutive i). Inner loads become
// lane-consecutive 16B = fully coalesced, 4 edges per instruction. Layer 0
// emits h in the same transposed layout (coalesced writes); layer 1 writes
// the final out[b][o] (1 MB scattered dword stores, negligible).
// Occupancy via S=4 i-split inside a 1024-thread block + LDS combine.

#define NB 256   // batch

// -------- transpose/pack: x[NB][INF] -> xT4[INF/4][NB] (float4 over i) -----
template<int INF>
__global__ __launch_bounds__(256) void pack_rows(
    const float* __restrict__ in, float4* __restrict__ outT4)
{
    __shared__ float t[64][65];                 // [b][i] tile, +1 pad
    const int bx = blockIdx.x % (INF / 64);     // i-tile
    const int by = blockIdx.x / (INF / 64);     // b-tile
    const int i0 = bx * 64, b0 = by * 64;

    const int li = threadIdx.x & 63;            // i within tile (lane -> coalesced)
    const int lb = threadIdx.x >> 6;            // 0..3
#pragma unroll
    for (int r = 0; r < 64; r += 4)
        t[lb + r][li] = in[(size_t)(b0 + lb + r) * INF + i0 + li];
    __syncthreads();

    const int sb = threadIdx.x & 63;            // b within tile (lane -> coalesced)
    const int si = threadIdx.x >> 6;            // 0..3
#pragma unroll
    for (int p = 0; p < 16; p += 4) {
        const int i4 = si + p;                  // 0..15 (16 float4 rows per tile)
        // LDS reads: stride-65 over lanes -> 2-way bank alias (free)
        float4 v = make_float4(t[sb][4 * i4 + 0], t[sb][4 * i4 + 1],
                               t[sb][4 * i4 + 2], t[sb][4 * i4 + 3]);
        outT4[(size_t)(i0 / 4 + i4) * NB + b0 + sb] = v;
    }
}

// -------- masked min/max layer over transposed input ----------------------
// TOUT=1: write output transposed (as float component of outT4 layout).
template<int INF, int OT, bool ISMIN, bool TOUT>
__global__ __launch_bounds__(1024) void daa_layer(
    const float4* __restrict__ inT4,   // [INF/4][NB]
    const int* __restrict__ sel,       // [OUTF][INF]
    float* __restrict__ out, int OUTF)
{
    constexpr int S  = 4;              // i-split wave groups
    constexpr int C4 = INF / 4 / S;    // float4 steps per group
    const int tid = threadIdx.x;
    const int b   = tid & 255;
    const int s   = tid >> 8;
    const int o0  = blockIdx.x * OT;
    const float off = ISMIN ? 2.0f : -1.0f;

    float acc[OT];
#pragma unroll
    for (int u = 0; u < OT; ++u) acc[u] = off;

    const float4* __restrict__ xp = inT4 + (size_t)s * C4 * NB + b;

#pragma unroll 2
    for (int i4 = 0; i4 < C4; ++i4) {
        const float4 xv = xp[(size_t)i4 * NB];           // coalesced 16B/lane
        const int ibase = (s * C4 + i4) * 4;
#pragma unroll
        for (int u = 0; u < OT; ++u) {
            // wave-uniform address -> single-line broadcast load
            const int4 sv = *(const int4*)(sel + (size_t)(o0 + u) * INF + ibase);
            const float v0 = sv.x ? xv.x : off;
            const float v1 = sv.y ? xv.y : off;
            const float v2 = sv.z ? xv.z : off;
            const float v3 = sv.w ? xv.w : off;
            if (ISMIN) acc[u] = fminf(acc[u], fminf(fminf(v0, v1), fminf(v2, v3)));
            else       acc[u] = fmaxf(acc[u], fmaxf(fmaxf(v0, v1), fmaxf(v2, v3)));
        }
    }

    // combine the S partials per (b,o) through LDS (lane-consecutive b ->
    // conflict-free)
    __shared__ float red[S][OT][NB];
#pragma unroll
    for (int u = 0; u < OT; ++u) red[s][u][b] = acc[u];
    __syncthreads();

    if (s == 0) {
#pragma unroll
        for (int u = 0; u < OT; ++u) {
            float v = acc[u];
#pragma unroll
            for (int ss = 1; ss < S; ++ss) {
                const float r = red[ss][u][b];
                v = ISMIN ? fminf(v, r) : fmaxf(v, r);
            }
            const int o = o0 + u;
            if (TOUT)  // transposed: component (o&3) of outT4[o>>2][b]
                out[((size_t)(o >> 2) * NB + b) * 4 + (o & 3)] = v;
            else
                out[(size_t)b * OUTF + o] = v;
        }
    }
}

extern "C" void kernel_launch(void* const* d_in, const int* in_sizes, int n_in,
                              void* d_out, int out_size, void* d_ws, size_t ws_size,
                              hipStream_t stream) {
    const float* x    = (const float*)d_in[0];  // [256,1024] f32
    const int*   sel0 = (const int*)d_in[1];    // [512,1024] i32
    const int*   sel1 = (const int*)d_in[2];    // [1024,512] i32
    float* out = (float*)d_out;                 // [256,1024] f32

    float4* xT4 = (float4*)d_ws;                            // [256][256] 1 MB
    float*  hT  = (float*)((char*)d_ws + (1 << 20));        // hT4 [128][256] 0.5 MB

    // pack x -> xT4: 64 blocks, ~1 MB r+w, L2-resident
    pack_rows<1024><<<64, 256, 0, stream>>>(x, xT4);
    // layer 0: 1024 -> 512, min. OT=2 -> 256 blocks x 16 waves (50% occ)
    daa_layer<1024, 2, true,  true ><<<512 / 2, 1024, 0, stream>>>(
        xT4, sel0, hT, 512);
    // layer 1: 512 -> 1024, max. OT=4 -> 256 blocks x 16 waves
    daa_layer< 512, 4, false, false><<<1024 / 4, 1024, 0, stream>>>(
        (const float4*)hT, sel1, out, 1024);
}

// Round 4
// 44.948 us; speedup vs baseline: 2.1079x; 1.2457x over previous
//
#include <hip/hip_runtime.h>

// DAA autoencoder: two masked-reduction layers.
//   layer0: h[b][o]   = min_i ( sel0[o][i] ? x[b][i] : 2.0f )   (t-norm)
//   layer1: out[b][o] = max_i ( sel1[o][i] ? h[b][i] : -1.0f )  (t-conorm)
// B=256, IN=1024, HID=512.
//
// R3 lesson: coalesced but still latency/issue-bound (VALUBusy ~20-40%).
// Fixes here:
//  * mask-as-addend: a[o][i] = sel ? 0.0f : +/-inf (pre-expanded); inner op
//    is  val = x + a  -> selected edges are x+0 = x bit-exact, deselected
//    become +/-inf and never win min/max. acc init = off (2.0/-1.0) so the
//    all-deselected row still returns the exact reference value.
//  * a[o][i] is wave-uniform; s laundered via readfirstlane so the compiler
//    proves uniformity -> s_load (scalar pipe), freeing the vector pipe.
//  * linear fminf/fmaxf chains -> v_min3/v_max3: 1.5 VALU/edge.
//  * block = 64 b-lanes x S=4 i-wave-groups, LDS combine; OT=4 so stores
//    are one float4 per lane. L0: 512 blocks, L1: 1024 blocks.

#define NB 256   // batch

// ---- pack x -> xT4[i4][b] AND expand sel -> float addend arrays ----------
template<int INF>
__global__ __launch_bounds__(256) void pack_expand(
    const float* __restrict__ in, float4* __restrict__ outT4,
    const int* __restrict__ sel0, float* __restrict__ a0,   // [512][1024]
    const int* __restrict__ sel1, float* __restrict__ a1)   // [1024][512]
{
    __shared__ float t[64][65];                 // [b][i] tile, +1 pad
    const int bx = blockIdx.x % (INF / 64);     // i-tile
    const int by = blockIdx.x / (INF / 64);     // b-tile
    const int i0 = bx * 64, b0 = by * 64;

    const int li = threadIdx.x & 63;
    const int lb = threadIdx.x >> 6;
#pragma unroll
    for (int r = 0; r < 64; r += 4)
        t[lb + r][li] = in[(size_t)(b0 + lb + r) * INF + i0 + li];

    // independent work while the LDS tile fills: expand both sel arrays.
    // 0 -> +/-inf (never wins min/max), 1 -> 0.0f (x + 0 == x exactly).
    {
        const int tid = blockIdx.x * 256 + threadIdx.x;   // 16384 threads
        const int4* s0 = (const int4*)sel0;  float4* d0 = (float4*)a0;
        const int4* s1 = (const int4*)sel1;  float4* d1 = (float4*)a1;
        const float pinf = __builtin_inff();
#pragma unroll
        for (int k = 0; k < 8; ++k) {          // 131072 int4 per array
            const int idx = tid + k * 16384;
            const int4 v = s0[idx];
            d0[idx] = make_float4(v.x ? 0.f : pinf, v.y ? 0.f : pinf,
                                  v.z ? 0.f : pinf, v.w ? 0.f : pinf);
            const int4 w = s1[idx];
            d1[idx] = make_float4(w.x ? 0.f : -pinf, w.y ? 0.f : -pinf,
                                  w.z ? 0.f : -pinf, w.w ? 0.f : -pinf);
        }
    }
    __syncthreads();

    const int sb = threadIdx.x & 63;
    const int si = threadIdx.x >> 6;
#pragma unroll
    for (int p = 0; p < 16; p += 4) {
        const int i4 = si + p;
        float4 v = make_float4(t[sb][4 * i4 + 0], t[sb][4 * i4 + 1],
                               t[sb][4 * i4 + 2], t[sb][4 * i4 + 3]);
        outT4[(size_t)(i0 / 4 + i4) * NB + b0 + sb] = v;
    }
}

// ---- masked min/max layer over transposed input ---------------------------
template<int INF, int OT, bool ISMIN, bool TOUT>
__global__ __launch_bounds__(256) void daa_layer(
    const float4* __restrict__ inT4,    // [INF/4][NB]
    const float* __restrict__ aexp,     // [OUTF][INF] float 0 / +/-inf
    float* __restrict__ out, int OUTF)
{
    constexpr int S  = 4;               // i-split wave groups (1 wave each)
    constexpr int C4 = INF / 4 / S;     // float4 steps per group
    const int lane = threadIdx.x & 63;
    const int s    = __builtin_amdgcn_readfirstlane(threadIdx.x >> 6);
    const int bch  = blockIdx.x & 3;    // b-chunk (64 batches)
    const int o0   = (blockIdx.x >> 2) * OT;
    const int b    = bch * 64 + lane;
    const float off = ISMIN ? 2.0f : -1.0f;

    float acc[OT];
#pragma unroll
    for (int u = 0; u < OT; ++u) acc[u] = off;

    const float4* __restrict__ xp = inT4 + (size_t)s * C4 * NB + b;
    const float4* __restrict__ ap[OT];
#pragma unroll
    for (int u = 0; u < OT; ++u)
        ap[u] = (const float4*)(aexp + (size_t)(o0 + u) * INF) + s * C4;

    // 4-deep x double-buffer: loads for chunk c+4 issue before computing c.
    float4 xv[4];
#pragma unroll
    for (int k = 0; k < 4; ++k) xv[k] = xp[(size_t)k * NB];

    for (int c = 0; c < C4; c += 4) {
        float4 xn[4];
        if (c + 4 < C4) {
#pragma unroll
            for (int k = 0; k < 4; ++k) xn[k] = xp[(size_t)(c + 4 + k) * NB];
        }
#pragma unroll
        for (int u = 0; u < OT; ++u) {
            float a = acc[u];
#pragma unroll
            for (int k = 0; k < 4; ++k) {
                const float4 av = ap[u][c + k];   // wave-uniform -> s_load
                const float4 x  = xv[k];
                if (ISMIN) {   // linear chains fuse to v_min3/v_max3
                    a = fminf(fminf(a, x.x + av.x), x.y + av.y);
                    a = fminf(fminf(a, x.z + av.z), x.w + av.w);
                } else {
                    a = fmaxf(fmaxf(a, x.x + av.x), x.y + av.y);
                    a = fmaxf(fmaxf(a, x.z + av.z), x.w + av.w);
                }
            }
            acc[u] = a;
        }
#pragma unroll
        for (int k = 0; k < 4; ++k) xv[k] = xn[k];
    }

    // combine the S=4 wave partials per (b,o) through LDS (lane-consecutive)
    __shared__ float red[S][OT][64];
#pragma unroll
    for (int u = 0; u < OT; ++u) red[s][u][lane] = acc[u];
    __syncthreads();

    if (threadIdx.x < 64) {
        float v[OT];
#pragma unroll
        for (int u = 0; u < OT; ++u) {
            const float r0 = red[0][u][lane], r1 = red[1][u][lane];
            const float r2 = red[2][u][lane], r3 = red[3][u][lane];
            v[u] = ISMIN ? fminf(fminf(r0, r1), fminf(r2, r3))
                         : fmaxf(fmaxf(r0, r1), fmaxf(r2, r3));
        }
        static_assert(OT == 4, "float4 store assumes OT==4");
        const float4 o4 = make_float4(v[0], v[1], v[2], v[3]);
        if (TOUT)   // transposed: float4 row (o0>>2), component = o&3
            ((float4*)out)[(size_t)(o0 >> 2) * NB + b] = o4;
        else        // out[b][o0..o0+3] contiguous
            *(float4*)(out + (size_t)b * OUTF + o0) = o4;
    }
}

extern "C" void kernel_launch(void* const* d_in, const int* in_sizes, int n_in,
                              void* d_out, int out_size, void* d_ws, size_t ws_size,
                              hipStream_t stream) {
    const float* x    = (const float*)d_in[0];  // [256,1024] f32
    const int*   sel0 = (const int*)d_in[1];    // [512,1024] i32
    const int*   sel1 = (const int*)d_in[2];    // [1024,512] i32
    float* out = (float*)d_out;                 // [256,1024] f32

    float4* xT4 = (float4*)d_ws;                                  // 1 MB
    float*  hT  = (float*)((char*)d_ws + (1 << 20));              // 0.5 MB
    float*  a0  = (float*)((char*)d_ws + (1 << 20) + (1 << 19));  // 2 MB
    float*  a1  = a0 + 512 * 1024;                                // 2 MB

    // pack x -> xT4, expand sel0/sel1 -> float addend arrays
    pack_expand<1024><<<64, 256, 0, stream>>>(x, xT4, sel0, a0, sel1, a1);
    // layer 0: 1024 -> 512, min. 128 o-tiles x 4 b-chunks = 512 blocks
    daa_layer<1024, 4, true,  true ><<<512,  256, 0, stream>>>(xT4, a0, hT, 512);
    // layer 1: 512 -> 1024, max. 256 o-tiles x 4 b-chunks = 1024 blocks
    daa_layer< 512, 4, false, false><<<1024, 256, 0, stream>>>(
        (const float4*)hT, a1, out, 1024);
}

// Round 5
// 30.927 us; speedup vs baseline: 3.0636x; 1.4534x over previous
//
#include <hip/hip_runtime.h>

// DAA autoencoder: two masked-reduction layers.
//   layer0: h[b][o]   = min_i ( sel0[o][i] ? x[b][i] : 2.0f )   (t-norm)
//   layer1: out[b][o] = max_i ( sel1[o][i] ? h[b][i] : -1.0f )  (t-conorm)
// B=256, IN=1024, HID=512.
//
// R4 lesson: 25% occupancy can't hide the ~200cy s_load latency (only
// ~48-96cy VALU per wave-iter); pack_expand used only 64 blocks.
// R5: S=8 i-split (512-thr blocks) -> L0 16 waves/CU, L1 32 waves/CU;
// pack_expand spread over 256 blocks.
//
// Core tricks (from R4, all bit-exact):
//  * mask-as-addend: a[o][i] = sel ? 0.0f : +/-inf; inner op is
//    val = x + a (selected -> x exactly; deselected -> +/-inf never wins).
//    acc init = off (2.0/-1.0) reproduces the all-deselected row exactly.
//  * a addresses wave-uniform (s laundered via readfirstlane) -> s_load,
//    scalar pipe; x loads coalesced float4 from transposed xT4[i4][b].
//  * linear fminf/fmaxf chains -> v_min3/v_max3: 1.5 VALU/edge.

#define NB 256   // batch

// ---- pack x -> xT4[i4][b] AND expand sel -> float addend arrays ----------
template<int INF>
__global__ __launch_bounds__(256) void pack_expand(
    const float* __restrict__ in, float4* __restrict__ outT4,
    const int* __restrict__ sel0, float* __restrict__ a0,   // [512][1024]
    const int* __restrict__ sel1, float* __restrict__ a1)   // [1024][512]
{
    // ---- sel expansion: split across all 256 blocks (65536 threads) ----
    {
        const int tid = blockIdx.x * 256 + threadIdx.x;
        const int4* s0 = (const int4*)sel0;  float4* d0 = (float4*)a0;
        const int4* s1 = (const int4*)sel1;  float4* d1 = (float4*)a1;
        const float pinf = __builtin_inff();
#pragma unroll
        for (int k = 0; k < 2; ++k) {          // 131072 int4 per array
            const int idx = tid + k * 65536;
            const int4 v = s0[idx];
            d0[idx] = make_float4(v.x ? 0.f : pinf, v.y ? 0.f : pinf,
                                  v.z ? 0.f : pinf, v.w ? 0.f : pinf);
            const int4 w = s1[idx];
            d1[idx] = make_float4(w.x ? 0.f : -pinf, w.y ? 0.f : -pinf,
                                  w.z ? 0.f : -pinf, w.w ? 0.f : -pinf);
        }
    }

    // ---- x transpose: blocks 0..63 only (2 MB of traffic) ----
    if (blockIdx.x < 64) {
        __shared__ float t[64][65];                 // [b][i] tile, +1 pad
        const int bx = blockIdx.x % (INF / 64);     // i-tile
        const int by = blockIdx.x / (INF / 64);     // b-tile
        const int i0 = bx * 64, b0 = by * 64;

        const int li = threadIdx.x & 63;
        const int lb = threadIdx.x >> 6;
#pragma unroll
        for (int r = 0; r < 64; r += 4)
            t[lb + r][li] = in[(size_t)(b0 + lb + r) * INF + i0 + li];
        __syncthreads();

        const int sb = threadIdx.x & 63;
        const int si = threadIdx.x >> 6;
#pragma unroll
        for (int p = 0; p < 16; p += 4) {
            const int i4 = si + p;
            float4 v = make_float4(t[sb][4 * i4 + 0], t[sb][4 * i4 + 1],
                                   t[sb][4 * i4 + 2], t[sb][4 * i4 + 3]);
            outT4[(size_t)(i0 / 4 + i4) * NB + b0 + sb] = v;
        }
    }
}

// ---- masked min/max layer over transposed input ---------------------------
template<int INF, int OT, bool ISMIN, bool TOUT>
__global__ __launch_bounds__(512) void daa_layer(
    const float4* __restrict__ inT4,    // [INF/4][NB]
    const float* __restrict__ aexp,     // [OUTF][INF] float 0 / +/-inf
    float* __restrict__ out, int OUTF)
{
    constexpr int S  = 8;               // i-split wave groups (1 wave each)
    constexpr int C4 = INF / 4 / S;     // float4 steps per group
    const int lane = threadIdx.x & 63;
    const int s    = __builtin_amdgcn_readfirstlane(threadIdx.x >> 6);
    const int bch  = blockIdx.x & 3;    // b-chunk (64 batches)
    const int o0   = (blockIdx.x >> 2) * OT;
    const int b    = bch * 64 + lane;
    const float off = ISMIN ? 2.0f : -1.0f;

    float acc[OT];
#pragma unroll
    for (int u = 0; u < OT; ++u) acc[u] = off;

    const float4* __restrict__ xp = inT4 + (size_t)s * C4 * NB + b;
    const float4* __restrict__ ap[OT];
#pragma unroll
    for (int u = 0; u < OT; ++u)
        ap[u] = (const float4*)(aexp + (size_t)(o0 + u) * INF) + s * C4;

    // 4-deep x pipeline: loads for chunk c+4 issue before computing c.
    float4 xv[4];
#pragma unroll
    for (int k = 0; k < 4; ++k) xv[k] = xp[(size_t)k * NB];

    for (int c = 0; c < C4; c += 4) {
        float4 xn[4];
        if (c + 4 < C4) {
#pragma unroll
            for (int k = 0; k < 4; ++k) xn[k] = xp[(size_t)(c + 4 + k) * NB];
        }
#pragma unroll
        for (int u = 0; u < OT; ++u) {
            float a = acc[u];
#pragma unroll
            for (int k = 0; k < 4; ++k) {
                const float4 av = ap[u][c + k];   // wave-uniform -> s_load
                const float4 x  = xv[k];
                if (ISMIN) {   // linear chains fuse to v_min3/v_max3
                    a = fminf(fminf(a, x.x + av.x), x.y + av.y);
                    a = fminf(fminf(a, x.z + av.z), x.w + av.w);
                } else {
                    a = fmaxf(fmaxf(a, x.x + av.x), x.y + av.y);
                    a = fmaxf(fmaxf(a, x.z + av.z), x.w + av.w);
                }
            }
            acc[u] = a;
        }
#pragma unroll
        for (int k = 0; k < 4; ++k) xv[k] = xn[k];
    }

    // combine the S=8 wave partials per (b,o) through LDS (lane-consecutive)
    __shared__ float red[S][OT][64];
#pragma unroll
    for (int u = 0; u < OT; ++u) red[s][u][lane] = acc[u];
    __syncthreads();

    if (threadIdx.x < 64) {
        float v[OT];
#pragma unroll
        for (int u = 0; u < OT; ++u) {
            float r = red[0][u][lane];
#pragma unroll
            for (int ss = 1; ss < S; ++ss) {
                const float q = red[ss][u][lane];
                r = ISMIN ? fminf(r, q) : fmaxf(r, q);
            }
            v[u] = r;
        }
        static_assert(OT == 4, "float4 store assumes OT==4");
        const float4 o4 = make_float4(v[0], v[1], v[2], v[3]);
        if (TOUT)   // transposed: float4 row (o0>>2), col b
            ((float4*)out)[(size_t)(o0 >> 2) * NB + b] = o4;
        else        // out[b][o0..o0+3] contiguous
            *(float4*)(out + (size_t)b * OUTF + o0) = o4;
    }
}

extern "C" void kernel_launch(void* const* d_in, const int* in_sizes, int n_in,
                              void* d_out, int out_size, void* d_ws, size_t ws_size,
                              hipStream_t stream) {
    const float* x    = (const float*)d_in[0];  // [256,1024] f32
    const int*   sel0 = (const int*)d_in[1];    // [512,1024] i32
    const int*   sel1 = (const int*)d_in[2];    // [1024,512] i32
    float* out = (float*)d_out;                 // [256,1024] f32

    float4* xT4 = (float4*)d_ws;                                  // 1 MB
    float*  hT  = (float*)((char*)d_ws + (1 << 20));              // 0.5 MB
    float*  a0  = (float*)((char*)d_ws + (1 << 20) + (1 << 19));  // 2 MB
    float*  a1  = a0 + 512 * 1024;                                // 2 MB

    // pack x -> xT4, expand sel0/sel1 -> float addend arrays (256 blocks)
    pack_expand<1024><<<256, 256, 0, stream>>>(x, xT4, sel0, a0, sel1, a1);
    // layer 0: 1024 -> 512, min. 128 o-tiles x 4 b-chunks = 512 blocks
    //          x 8 waves -> 16 waves/CU (50% occ)
    daa_layer<1024, 4, true,  true ><<<512,  512, 0, stream>>>(xT4, a0, hT, 512);
    // layer 1: 512 -> 1024, max. 256 o-tiles x 4 b-chunks = 1024 blocks
    //          x 8 waves -> 32 waves/CU (~100% occ)
    daa_layer< 512, 4, false, false><<<1024, 512, 0, stream>>>(
        (const float4*)hT, a1, out, 1024);
}

// Round 6
// 28.131 us; speedup vs baseline: 3.3680x; 1.0994x over previous
//
#include <hip/hip_runtime.h>

// DAA autoencoder: two masked-reduction layers.
//   layer0: h[b][o]   = min_i ( sel0[o][i] ? x[b][i] : 2.0f )   (t-norm)
//   layer1: out[b][o] = max_i ( sel1[o][i] ? h[b][i] : -1.0f )  (t-conorm)
// B=256, IN=1024, HID=512.
//
// R5 lesson: L0 at 50% occupancy left s_load latency exposed. R6: L0 S=16
// (1024-thr blocks) -> 32 waves/CU; launch_bounds(...,8) caps VGPR at 64 so
// occupancy is real; x-prefetch shrunk 4->2 deep to fit (TLP > ILP at 8
// waves/SIMD). pack_expand spread over 512 blocks, 1 int4/thread.
//
// Core tricks (bit-exact):
//  * mask-as-addend: a[o][i] = sel ? 0.0f : +/-inf; inner op is
//    val = x + a (selected -> x exactly; deselected -> +/-inf never wins).
//    acc init = off (2.0/-1.0) reproduces the all-deselected row exactly.
//  * a addresses wave-uniform (s laundered via readfirstlane) -> s_load,
//    scalar pipe; x loads coalesced float4 from transposed xT4[i4][b].
//  * linear fminf/fmaxf chains -> v_min3/v_max3: 1.5 VALU/edge.

#define NB 256   // batch

// ---- pack x -> xT4[i4][b] AND expand sel -> float addend arrays ----------
template<int INF>
__global__ __launch_bounds__(256) void pack_expand(
    const float* __restrict__ in, float4* __restrict__ outT4,
    const int* __restrict__ sel0, float* __restrict__ a0,   // [512][1024]
    const int* __restrict__ sel1, float* __restrict__ a1)   // [1024][512]
{
    // ---- sel expansion: 512 blocks x 256 thr = 131072 threads, 1 int4 each
    {
        const int idx = blockIdx.x * 256 + threadIdx.x;
        const int4* s0 = (const int4*)sel0;  float4* d0 = (float4*)a0;
        const int4* s1 = (const int4*)sel1;  float4* d1 = (float4*)a1;
        const float pinf = __builtin_inff();
        const int4 v = s0[idx];
        d0[idx] = make_float4(v.x ? 0.f : pinf, v.y ? 0.f : pinf,
                              v.z ? 0.f : pinf, v.w ? 0.f : pinf);
        const int4 w = s1[idx];
        d1[idx] = make_float4(w.x ? 0.f : -pinf, w.y ? 0.f : -pinf,
                              w.z ? 0.f : -pinf, w.w ? 0.f : -pinf);
    }

    // ---- x transpose: blocks 0..63 only (2 MB of traffic) ----
    if (blockIdx.x < 64) {
        __shared__ float t[64][65];                 // [b][i] tile, +1 pad
        const int bx = blockIdx.x % (INF / 64);     // i-tile
        const int by = blockIdx.x / (INF / 64);     // b-tile
        const int i0 = bx * 64, b0 = by * 64;

        const int li = threadIdx.x & 63;
        const int lb = threadIdx.x >> 6;
#pragma unroll
        for (int r = 0; r < 64; r += 4)
            t[lb + r][li] = in[(size_t)(b0 + lb + r) * INF + i0 + li];
        __syncthreads();

        const int sb = threadIdx.x & 63;
        const int si = threadIdx.x >> 6;
#pragma unroll
        for (int p = 0; p < 16; p += 4) {
            const int i4 = si + p;
            float4 v = make_float4(t[sb][4 * i4 + 0], t[sb][4 * i4 + 1],
                                   t[sb][4 * i4 + 2], t[sb][4 * i4 + 3]);
            outT4[(size_t)(i0 / 4 + i4) * NB + b0 + sb] = v;
        }
    }
}

// ---- masked min/max layer over transposed input ---------------------------
template<int INF, int OT, int S, bool ISMIN, bool TOUT>
__global__ __launch_bounds__(64 * S, 8) void daa_layer(
    const float4* __restrict__ inT4,    // [INF/4][NB]
    const float* __restrict__ aexp,     // [OUTF][INF] float 0 / +/-inf
    float* __restrict__ out, int OUTF)
{
    constexpr int C4 = INF / 4 / S;     // float4 steps per wave group
    const int lane = threadIdx.x & 63;
    const int s    = __builtin_amdgcn_readfirstlane(threadIdx.x >> 6);
    const int bch  = blockIdx.x & 3;    // b-chunk (64 batches)
    const int o0   = (blockIdx.x >> 2) * OT;
    const int b    = bch * 64 + lane;
    const float off = ISMIN ? 2.0f : -1.0f;

    float acc[OT];
#pragma unroll
    for (int u = 0; u < OT; ++u) acc[u] = off;

    const float4* __restrict__ xp = inT4 + (size_t)s * C4 * NB + b;
    const float4* __restrict__ ap[OT];
#pragma unroll
    for (int u = 0; u < OT; ++u)
        ap[u] = (const float4*)(aexp + (size_t)(o0 + u) * INF) + s * C4;

    // 2-deep x pipeline (TLP at 8 waves/SIMD does the rest of the hiding)
    float4 xv[2];
#pragma unroll
    for (int k = 0; k < 2; ++k) xv[k] = xp[(size_t)k * NB];

    for (int c = 0; c < C4; c += 2) {
        float4 xn[2];
        if (c + 2 < C4) {
#pragma unroll
            for (int k = 0; k < 2; ++k) xn[k] = xp[(size_t)(c + 2 + k) * NB];
        }
#pragma unroll
        for (int u = 0; u < OT; ++u) {
            float a = acc[u];
#pragma unroll
            for (int k = 0; k < 2; ++k) {
                const float4 av = ap[u][c + k];   // wave-uniform -> s_load
                const float4 x  = xv[k];
                if (ISMIN) {   // linear chains fuse to v_min3/v_max3
                    a = fminf(fminf(a, x.x + av.x), x.y + av.y);
                    a = fminf(fminf(a, x.z + av.z), x.w + av.w);
                } else {
                    a = fmaxf(fmaxf(a, x.x + av.x), x.y + av.y);
                    a = fmaxf(fmaxf(a, x.z + av.z), x.w + av.w);
                }
            }
            acc[u] = a;
        }
#pragma unroll
        for (int k = 0; k < 2; ++k) xv[k] = xn[k];
    }

    // combine the S wave partials per (b,o) through LDS (lane-consecutive)
    __shared__ float red[S][OT][64];
#pragma unroll
    for (int u = 0; u < OT; ++u) red[s][u][lane] = acc[u];
    __syncthreads();

    if (threadIdx.x < 64) {
        float v[OT];
#pragma unroll
        for (int u = 0; u < OT; ++u) {
            float r = red[0][u][lane];
#pragma unroll
            for (int ss = 1; ss < S; ++ss) {
                const float q = red[ss][u][lane];
                r = ISMIN ? fminf(r, q) : fmaxf(r, q);
            }
            v[u] = r;
        }
        static_assert(OT == 4, "float4 store assumes OT==4");
        const float4 o4 = make_float4(v[0], v[1], v[2], v[3]);
        if (TOUT)   // transposed: float4 row (o0>>2), col b
            ((float4*)out)[(size_t)(o0 >> 2) * NB + b] = o4;
        else        // out[b][o0..o0+3] contiguous
            *(float4*)(out + (size_t)b * OUTF + o0) = o4;
    }
}

extern "C" void kernel_launch(void* const* d_in, const int* in_sizes, int n_in,
                              void* d_out, int out_size, void* d_ws, size_t ws_size,
                              hipStream_t stream) {
    const float* x    = (const float*)d_in[0];  // [256,1024] f32
    const int*   sel0 = (const int*)d_in[1];    // [512,1024] i32
    const int*   sel1 = (const int*)d_in[2];    // [1024,512] i32
    float* out = (float*)d_out;                 // [256,1024] f32

    float4* xT4 = (float4*)d_ws;                                  // 1 MB
    float*  hT  = (float*)((char*)d_ws + (1 << 20));              // 0.5 MB
    float*  a0  = (float*)((char*)d_ws + (1 << 20) + (1 << 19));  // 2 MB
    float*  a1  = a0 + 512 * 1024;                                // 2 MB

    // pack x -> xT4, expand sel0/sel1 -> float addend arrays
    pack_expand<1024><<<512, 256, 0, stream>>>(x, xT4, sel0, a0, sel1, a1);
    // layer 0: 1024 -> 512, min. 128 o-tiles x 4 b-chunks = 512 blocks
    //          x 16 waves (S=16) -> 2 blocks/CU = 32 waves/CU (100% occ)
    daa_layer<1024, 4, 16, true,  true ><<<512,  1024, 0, stream>>>(
        xT4, a0, hT, 512);
    // layer 1: 512 -> 1024, max. 256 o-tiles x 4 b-chunks = 1024 blocks
    //          x 8 waves (S=8) -> 4 blocks/CU = 32 waves/CU (100% occ)
    daa_layer< 512, 4, 8, false, false><<<1024, 512, 0, stream>>>(
        (const float4*)hT, a1, out, 1024);
}

// Round 7
// 27.264 us; speedup vs baseline: 3.4751x; 1.0318x over previous
//
#include <hip/hip_runtime.h>

// DAA autoencoder: two masked-reduction layers.
//   layer0: h[b][o]   = min_i ( sel0[o][i] ? x[b][i] : 2.0f )   (t-norm)
//   layer1: out[b][o] = max_i ( sel1[o][i] ? h[b][i] : -1.0f )  (t-conorm)
// B=256, IN=1024, HID=512.
//
// R6 lesson: occupancy maxed but still ~2x over floor -> the 8 wave-uniform
// s_load_dwordx4/iter thrash the scalar cache (32 KB working set/CU), and
// all waves miss on the same lines so TLP can't hide it. R7: stage the
// addend rows in LDS once per block (coalesced), inner loop reads them via
// wave-uniform ds_read_b128 broadcasts (no bank conflicts, pipelined lgkm).
//
// Core tricks (bit-exact):
//  * mask-as-addend: a[o][i] = sel ? 0.0f : +/-inf; inner op is
//    val = x + a (selected -> x exactly; deselected -> +/-inf never wins).
//    acc init = off (2.0/-1.0) reproduces the all-deselected row exactly.
//  * x loads coalesced float4 from transposed xT4[i4][b], 2-deep prefetch.
//  * linear fminf/fmaxf chains -> v_min3/v_max3: 1.5 VALU/edge.

#define NB 256   // batch

// ---- pack x -> xT4[i4][b] AND expand sel -> float addend arrays ----------
template<int INF>
__global__ __launch_bounds__(256) void pack_expand(
    const float* __restrict__ in, float4* __restrict__ outT4,
    const int* __restrict__ sel0, float* __restrict__ a0,   // [512][1024]
    const int* __restrict__ sel1, float* __restrict__ a1)   // [1024][512]
{
    // ---- sel expansion: 512 blocks x 256 thr = 131072 threads, 1 int4 each
    {
        const int idx = blockIdx.x * 256 + threadIdx.x;
        const int4* s0 = (const int4*)sel0;  float4* d0 = (float4*)a0;
        const int4* s1 = (const int4*)sel1;  float4* d1 = (float4*)a1;
        const float pinf = __builtin_inff();
        const int4 v = s0[idx];
        d0[idx] = make_float4(v.x ? 0.f : pinf, v.y ? 0.f : pinf,
                              v.z ? 0.f : pinf, v.w ? 0.f : pinf);
        const int4 w = s1[idx];
        d1[idx] = make_float4(w.x ? 0.f : -pinf, w.y ? 0.f : -pinf,
                              w.z ? 0.f : -pinf, w.w ? 0.f : -pinf);
    }

    // ---- x transpose: blocks 0..63 only (2 MB of traffic) ----
    if (blockIdx.x < 64) {
        __shared__ float t[64][65];                 // [b][i] tile, +1 pad
        const int bx = blockIdx.x % (INF / 64);     // i-tile
        const int by = blockIdx.x / (INF / 64);     // b-tile
        const int i0 = bx * 64, b0 = by * 64;

        const int li = threadIdx.x & 63;
        const int lb = threadIdx.x >> 6;
#pragma unroll
        for (int r = 0; r < 64; r += 4)
            t[lb + r][li] = in[(size_t)(b0 + lb + r) * INF + i0 + li];
        __syncthreads();

        const int sb = threadIdx.x & 63;
        const int si = threadIdx.x >> 6;
#pragma unroll
        for (int p = 0; p < 16; p += 4) {
            const int i4 = si + p;
            float4 v = make_float4(t[sb][4 * i4 + 0], t[sb][4 * i4 + 1],
                                   t[sb][4 * i4 + 2], t[sb][4 * i4 + 3]);
            outT4[(size_t)(i0 / 4 + i4) * NB + b0 + sb] = v;
        }
    }
}

// ---- masked min/max layer over transposed input ---------------------------
template<int INF, int OT, int S, bool ISMIN, bool TOUT>
__global__ __launch_bounds__(64 * S, 8) void daa_layer(
    const float4* __restrict__ inT4,    // [INF/4][NB]
    const float* __restrict__ aexp,     // [OUTF][INF] float 0 / +/-inf
    float* __restrict__ out, int OUTF)
{
    constexpr int C4  = INF / 4 / S;    // float4 steps per wave group
    constexpr int NF4 = OT * INF / 4;   // addend float4s per block
    const int lane = threadIdx.x & 63;
    const int s    = __builtin_amdgcn_readfirstlane(threadIdx.x >> 6);
    const int bch  = blockIdx.x & 3;    // b-chunk (64 batches)
    const int o0   = (blockIdx.x >> 2) * OT;
    const int b    = bch * 64 + lane;
    const float off = ISMIN ? 2.0f : -1.0f;

    // ---- stage the OT addend rows in LDS (rows o0..o0+OT-1 contiguous) ----
    __shared__ float4 aLDS[NF4];
    {
        const float4* asrc = (const float4*)(aexp + (size_t)o0 * INF);
        for (int idx = threadIdx.x; idx < NF4; idx += 64 * S)
            aLDS[idx] = asrc[idx];
    }
    __syncthreads();

    float acc[OT];
#pragma unroll
    for (int u = 0; u < OT; ++u) acc[u] = off;

    const float4* __restrict__ xp = inT4 + (size_t)s * C4 * NB + b;

    // 2-deep x pipeline (TLP at 8 waves/SIMD does the rest of the hiding)
    float4 xv[2];
#pragma unroll
    for (int k = 0; k < 2; ++k) xv[k] = xp[(size_t)k * NB];

    for (int c = 0; c < C4; c += 2) {
        float4 xn[2];
        if (c + 2 < C4) {
#pragma unroll
            for (int k = 0; k < 2; ++k) xn[k] = xp[(size_t)(c + 2 + k) * NB];
        }
#pragma unroll
        for (int u = 0; u < OT; ++u) {
            float a = acc[u];
#pragma unroll
            for (int k = 0; k < 2; ++k) {
                // wave-uniform LDS address -> ds_read_b128 broadcast
                const float4 av = aLDS[u * (INF / 4) + s * C4 + c + k];
                const float4 x  = xv[k];
                if (ISMIN) {   // linear chains fuse to v_min3/v_max3
                    a = fminf(fminf(a, x.x + av.x), x.y + av.y);
                    a = fminf(fminf(a, x.z + av.z), x.w + av.w);
                } else {
                    a = fmaxf(fmaxf(a, x.x + av.x), x.y + av.y);
                    a = fmaxf(fmaxf(a, x.z + av.z), x.w + av.w);
                }
            }
            acc[u] = a;
        }
#pragma unroll
        for (int k = 0; k < 2; ++k) xv[k] = xn[k];
    }

    // combine the S wave partials per (b,o) through LDS (lane-consecutive)
    __shared__ float red[S][OT][64];
#pragma unroll
    for (int u = 0; u < OT; ++u) red[s][u][lane] = acc[u];
    __syncthreads();

    if (threadIdx.x < 64) {
        float v[OT];
#pragma unroll
        for (int u = 0; u < OT; ++u) {
            float r = red[0][u][lane];
#pragma unroll
            for (int ss = 1; ss < S; ++ss) {
                const float q = red[ss][u][lane];
                r = ISMIN ? fminf(r, q) : fmaxf(r, q);
            }
            v[u] = r;
        }
        static_assert(OT == 4, "float4 store assumes OT==4");
        const float4 o4 = make_float4(v[0], v[1], v[2], v[3]);
        if (TOUT)   // transposed: float4 row (o0>>2), col b
            ((float4*)out)[(size_t)(o0 >> 2) * NB + b] = o4;
        else        // out[b][o0..o0+3] contiguous
            *(float4*)(out + (size_t)b * OUTF + o0) = o4;
    }
}

extern "C" void kernel_launch(void* const* d_in, const int* in_sizes, int n_in,
                              void* d_out, int out_size, void* d_ws, size_t ws_size,
                              hipStream_t stream) {
    const float* x    = (const float*)d_in[0];  // [256,1024] f32
    const int*   sel0 = (const int*)d_in[1];    // [512,1024] i32
    const int*   sel1 = (const int*)d_in[2];    // [1024,512] i32
    float* out = (float*)d_out;                 // [256,1024] f32

    float4* xT4 = (float4*)d_ws;                                  // 1 MB
    float*  hT  = (float*)((char*)d_ws + (1 << 20));              // 0.5 MB
    float*  a0  = (float*)((char*)d_ws + (1 << 20) + (1 << 19));  // 2 MB
    float*  a1  = a0 + 512 * 1024;                                // 2 MB

    // pack x -> xT4, expand sel0/sel1 -> float addend arrays
    pack_expand<1024><<<512, 256, 0, stream>>>(x, xT4, sel0, a0, sel1, a1);
    // layer 0: 1024 -> 512, min. 128 o-tiles x 4 b-chunks = 512 blocks
    //          x 16 waves (S=16) -> 2 blocks/CU = 32 waves/CU (100% occ)
    //          LDS: 16K addends + 16K red = 32 KB
    daa_layer<1024, 4, 16, true,  true ><<<512,  1024, 0, stream>>>(
        xT4, a0, hT, 512);
    // layer 1: 512 -> 1024, max. 256 o-tiles x 4 b-chunks = 1024 blocks
    //          x 8 waves (S=8) -> 4 blocks/CU = 32 waves/CU (100% occ)
    //          LDS: 8K addends + 8K red = 16 KB
    daa_layer< 512, 4, 8, false, false><<<1024, 512, 0, stream>>>(
        (const float4*)hT, a1, out, 1024);
}